// Round 1
// baseline (3853.286 us; speedup 1.0000x reference)
//
#include <hip/hip_runtime.h>
#include <hip/hip_bf16.h>
#include <math.h>

#define IGNORE_INDEX (-100)
#define BETA 0.1f

typedef __bf16 bf16x8 __attribute__((ext_vector_type(8)));
typedef float f32x4 __attribute__((ext_vector_type(4)));

static constexpr int Bsz = 8, T = 1024, H = 4096, V = 32000;
static constexpr int M = Bsz * T;       // 8192 tokens
static constexpr int BM = 128, BN = 128, BK = 64;
static constexpr int MT = M / BM;       // 64
static constexpr int NT = V / BN;       // 250
static constexpr int NSTRIP = NT * 2;   // 500 strips of 64 cols

// ---------------------------------------------------------------- fp32->bf16
__global__ void cvt_bf16_kernel(const float* __restrict__ src,
                                __bf16* __restrict__ dst, int n) {
  int stride = gridDim.x * blockDim.x * 8;
  for (int i = (blockIdx.x * blockDim.x + threadIdx.x) * 8; i < n; i += stride) {
    float4 v0 = *(const float4*)(src + i);
    float4 v1 = *(const float4*)(src + i + 4);
    bf16x8 o;
    o[0] = (__bf16)v0.x; o[1] = (__bf16)v0.y; o[2] = (__bf16)v0.z; o[3] = (__bf16)v0.w;
    o[4] = (__bf16)v1.x; o[5] = (__bf16)v1.y; o[6] = (__bf16)v1.z; o[7] = (__bf16)v1.w;
    *(bf16x8*)(dst + i) = o;
  }
}

__device__ inline void gload_lds16(const void* g, void* l) {
  __builtin_amdgcn_global_load_lds(
      (const __attribute__((address_space(1))) void*)g,
      (__attribute__((address_space(3))) void*)l, 16, 0, 0);
}

// ------------------------------------------------- fused GEMM + strip-LSE
// A: [M][H] bf16 (tokens), W: [V][H] bf16 (B^T layout), bias fp32[V]
// Writes per-strip (max, sumexp) partials[token][strip] and label logits.
__global__ __launch_bounds__(256) void gemm_lse_kernel(
    const __bf16* __restrict__ A, const __bf16* __restrict__ W,
    const float* __restrict__ bias, const int* __restrict__ target,
    float2* __restrict__ partials, float* __restrict__ label_logit) {
  __shared__ __bf16 ldsA[BM * BK];
  __shared__ __bf16 ldsB[BN * BK];

  // bijective XCD swizzle (16000 % 8 == 0), mt-fastest for B-panel L2 reuse
  int bid = blockIdx.x;
  int swz = (bid & 7) * (MT * NT / 8) + (bid >> 3);
  int mt = swz % MT;
  int nt = swz / MT;

  int tid = threadIdx.x;
  int lane = tid & 63;
  int wid = tid >> 6;               // 4 waves
  int wr = wid >> 1, wc = wid & 1;  // 2x2 wave grid, 64x64 each

  f32x4 acc[4][4];
#pragma unroll
  for (int m = 0; m < 4; ++m)
#pragma unroll
    for (int n = 0; n < 4; ++n) acc[m][n] = (f32x4){0.f, 0.f, 0.f, 0.f};

  int skb = (lane & 7) * 8;  // k-offset of this lane's 16B chunk
  const __bf16* gA = A + (size_t)(mt * BM) * H + skb;
  const __bf16* gB = W + (size_t)(nt * BN) * H + skb;

  for (int kt = 0; kt < H / BK; ++kt) {
    int k0 = kt * BK;
#pragma unroll
    for (int i = 0; i < 4; ++i) {
      int r = (wid * 4 + i) * 8 + (lane >> 3);
      gload_lds16(gA + (size_t)r * H + k0, &ldsA[(wid * 4 + i) * 512]);
    }
#pragma unroll
    for (int i = 0; i < 4; ++i) {
      int r = (wid * 4 + i) * 8 + (lane >> 3);
      gload_lds16(gB + (size_t)r * H + k0, &ldsB[(wid * 4 + i) * 512]);
    }
    __syncthreads();  // drains vmcnt -> LDS tiles ready
#pragma unroll
    for (int kk = 0; kk < BK; kk += 32) {
      bf16x8 af[4], bfr[4];
#pragma unroll
      for (int m = 0; m < 4; ++m)
        af[m] = *(const bf16x8*)&ldsA[(wr * 64 + m * 16 + (lane & 15)) * BK + kk + (lane >> 4) * 8];
#pragma unroll
      for (int n = 0; n < 4; ++n)
        bfr[n] = *(const bf16x8*)&ldsB[(wc * 64 + n * 16 + (lane & 15)) * BK + kk + (lane >> 4) * 8];
#pragma unroll
      for (int m = 0; m < 4; ++m)
#pragma unroll
        for (int n = 0; n < 4; ++n)
          acc[m][n] = __builtin_amdgcn_mfma_f32_16x16x32_bf16(af[m], bfr[n], acc[m][n], 0, 0, 0);
    }
    __syncthreads();  // protect LDS from next stage
  }

  // epilogue: bias add, per-row strip max/sumexp, label extraction
  int cbase = nt * BN + wc * 64 + (lane & 15);
  float bv[4];
#pragma unroll
  for (int n = 0; n < 4; ++n) bv[n] = bias[cbase + n * 16];
  int strip = nt * 2 + wc;

#pragma unroll
  for (int m = 0; m < 4; ++m) {
#pragma unroll
    for (int j = 0; j < 4; ++j) {
      int tr = mt * BM + wr * 64 + m * 16 + (lane >> 4) * 4 + j;
      float v0 = acc[m][0][j] + bv[0];
      float v1 = acc[m][1][j] + bv[1];
      float v2 = acc[m][2][j] + bv[2];
      float v3 = acc[m][3][j] + bv[3];
      float rmax = fmaxf(fmaxf(v0, v1), fmaxf(v2, v3));
#pragma unroll
      for (int off = 8; off; off >>= 1) rmax = fmaxf(rmax, __shfl_xor(rmax, off));
      float s = expf(v0 - rmax) + expf(v1 - rmax) + expf(v2 - rmax) + expf(v3 - rmax);
#pragma unroll
      for (int off = 8; off; off >>= 1) s += __shfl_xor(s, off);
      if ((lane & 15) == 0) partials[(size_t)tr * NSTRIP + strip] = make_float2(rmax, s);
      int lbl = target[tr];
      if (lbl == cbase) label_logit[tr] = v0;
      else if (lbl == cbase + 16) label_logit[tr] = v1;
      else if (lbl == cbase + 32) label_logit[tr] = v2;
      else if (lbl == cbase + 48) label_logit[tr] = v3;
    }
  }
}

// ------------------------------------------------- per-token LSE combine
__global__ void lse_kernel(const float2* __restrict__ partials,
                           const float* __restrict__ label_logit,
                           const int* __restrict__ target,
                           float* __restrict__ token_logp) {
  int t = blockIdx.x;
  int lane = threadIdx.x;  // 64
  const float2* p = partials + (size_t)t * NSTRIP;
  float m = -INFINITY, s = 0.f;
  for (int i = lane; i < NSTRIP; i += 64) {
    float2 q = p[i];
    float nm = fmaxf(m, q.x);
    s = s * expf(m - nm) + q.y * expf(q.x - nm);
    m = nm;
  }
  float M2 = m;
#pragma unroll
  for (int off = 32; off; off >>= 1) M2 = fmaxf(M2, __shfl_xor(M2, off));
  float s2 = (m == -INFINITY) ? 0.f : s * expf(m - M2);
#pragma unroll
  for (int off = 32; off; off >>= 1) s2 += __shfl_xor(s2, off);
  if (lane == 0) {
    float lse = M2 + logf(s2);
    int lbl = target[t];
    token_logp[t] = (lbl != IGNORE_INDEX) ? (label_logit[t] - lse) : 0.f;
  }
}

// ------------------------------------------------- final scalar loss
__global__ void final_kernel(const float* __restrict__ token_logp,
                             const int* __restrict__ target,
                             float* __restrict__ out) {
  __shared__ float red[4];
  __shared__ float seq[8];
  int tid = threadIdx.x;  // 256
  int lane = tid & 63, w = tid >> 6;
  for (int b = 0; b < 8; ++b) {
    float s = 0.f;
    for (int t = tid; t < T; t += 256) s += token_logp[b * T + t];
#pragma unroll
    for (int off = 32; off; off >>= 1) s += __shfl_xor(s, off);
    if (lane == 0) red[w] = s;
    __syncthreads();
    if (tid == 0) seq[b] = red[0] + red[1] + red[2] + red[3];
    __syncthreads();
  }
  float c = 0.f;
  for (int t = tid; t < 4 * T; t += 256) c += (target[t] != IGNORE_INDEX) ? 1.f : 0.f;
#pragma unroll
  for (int off = 32; off; off >>= 1) c += __shfl_xor(c, off);
  if (lane == 0) red[w] = c;
  __syncthreads();
  if (tid == 0) {
    float cnt = red[0] + red[1] + red[2] + red[3];
    float nll = -(seq[0] + seq[1] + seq[2] + seq[3]) / cnt;
    float pref = 0.f;
    for (int i = 0; i < 4; ++i) {
      float d = BETA * (seq[i] - seq[i + 4]);
      float ls = fminf(d, 0.f) - log1pf(expf(-fabsf(d)));  // log_sigmoid(d)
      pref += -ls;
    }
    pref *= 0.25f;
    out[0] = nll + pref;
  }
}

extern "C" void kernel_launch(void* const* d_in, const int* in_sizes, int n_in,
                              void* d_out, int out_size, void* d_ws, size_t ws_size,
                              hipStream_t stream) {
  const float* lin_weight = (const float*)d_in[0];  // [V][H]
  const float* input = (const float*)d_in[1];       // [B][T][H]
  const int* target = (const int*)d_in[2];          // [B][T]
  const float* bias = (const float*)d_in[3];        // [V]
  float* out = (float*)d_out;

  char* ws = (char*)d_ws;
  __bf16* Abf = (__bf16*)ws;
  size_t o = (size_t)M * H * 2;
  __bf16* Wbf = (__bf16*)(ws + o);
  o += (size_t)V * H * 2;
  float2* partials = (float2*)(ws + o);
  o += (size_t)M * NSTRIP * 8;
  float* label_logit = (float*)(ws + o);
  o += (size_t)M * 4;
  float* token_logp = (float*)(ws + o);

  cvt_bf16_kernel<<<2048, 256, 0, stream>>>(input, Abf, M * H);
  cvt_bf16_kernel<<<4096, 256, 0, stream>>>(lin_weight, Wbf, V * H);
  gemm_lse_kernel<<<MT * NT, 256, 0, stream>>>(Abf, Wbf, bias, target, partials, label_logit);
  lse_kernel<<<M, 64, 0, stream>>>(partials, label_logit, target, token_logp);
  final_kernel<<<1, 256, 0, stream>>>(token_logp, target, out);
}

// Round 2
// 2353.193 us; speedup vs baseline: 1.6375x; 1.6375x over previous
//
#include <hip/hip_runtime.h>
#include <hip/hip_bf16.h>
#include <math.h>

#define IGNORE_INDEX (-100)
#define BETA 0.1f

typedef float f32x4 __attribute__((ext_vector_type(4)));
typedef long long i64frag;

static constexpr int Bsz = 8, T = 1024, H = 4096, V = 32000;
static constexpr int M = Bsz * T;       // 8192 tokens
static constexpr int BM = 128, BN = 128, BK = 128;  // BK in fp8 bytes
static constexpr int MT = M / BM;       // 64
static constexpr int NT = V / BN;       // 250
static constexpr int NSTRIP = NT * 2;   // 500 strips of 64 cols

// ------------------------------------------------- fp32 -> fp8 e4m3 (packed)
__global__ void cvt_fp8_kernel(const float* __restrict__ src,
                               uint2* __restrict__ dst, int n8) {
  int stride = gridDim.x * blockDim.x;
  for (int g = blockIdx.x * blockDim.x + threadIdx.x; g < n8; g += stride) {
    const float4* s = (const float4*)(src + (size_t)g * 8);
    float4 v0 = s[0], v1 = s[1];
    int r0 = __builtin_amdgcn_cvt_pk_fp8_f32(v0.x, v0.y, 0, false);
    r0 = __builtin_amdgcn_cvt_pk_fp8_f32(v0.z, v0.w, r0, true);
    int r1 = __builtin_amdgcn_cvt_pk_fp8_f32(v1.x, v1.y, 0, false);
    r1 = __builtin_amdgcn_cvt_pk_fp8_f32(v1.z, v1.w, r1, true);
    dst[g] = make_uint2((unsigned)r0, (unsigned)r1);
  }
}

__device__ inline void gload_lds16(const void* g, void* l) {
  __builtin_amdgcn_global_load_lds(
      (const __attribute__((address_space(1))) void*)g,
      (__attribute__((address_space(3))) void*)l, 16, 0, 0);
}

// ------------------------------------------------- fused fp8 GEMM + strip-LSE
// A: [M][H] fp8, W: [V][H] fp8 (B^T layout), bias fp32[V]
// T2 swizzle: global source chunk pre-permuted (chunk ^= row&7), LDS linear,
// ds_read applies the same XOR -> both-sides involution (rule 21).
__global__ __launch_bounds__(256) void gemm_lse_kernel(
    const unsigned char* __restrict__ A, const unsigned char* __restrict__ W,
    const float* __restrict__ bias, const int* __restrict__ target,
    float2* __restrict__ partials, float* __restrict__ label_logit) {
  __shared__ unsigned char ldsA[BM * BK];
  __shared__ unsigned char ldsB[BN * BK];

  // bijective XCD swizzle (16000 % 8 == 0), mt-fastest for W-panel L2 reuse
  int bid = blockIdx.x;
  int swz = (bid & 7) * (MT * NT / 8) + (bid >> 3);
  int mt = swz % MT;
  int nt = swz / MT;

  int tid = threadIdx.x;
  int lane = tid & 63;
  int wid = tid >> 6;               // 4 waves
  int wr = wid >> 1, wc = wid & 1;  // 2x2 wave grid, 64x64 each

  f32x4 acc[4][4];
#pragma unroll
  for (int m = 0; m < 4; ++m)
#pragma unroll
    for (int n = 0; n < 4; ++n) acc[m][n] = (f32x4){0.f, 0.f, 0.f, 0.f};

  int lrow8 = lane >> 3;             // row within the 8-row staging stripe
  int csrc = (lane & 7) ^ lrow8;     // pre-swizzled source chunk (R&7 == lrow8)
  const unsigned char* gA = A + (size_t)(mt * BM) * H;
  const unsigned char* gB = W + (size_t)(nt * BN) * H;

  for (int kt = 0; kt < H / BK; ++kt) {
    size_t k0 = (size_t)kt * BK;
#pragma unroll
    for (int i = 0; i < 4; ++i) {
      int R = (wid * 4 + i) * 8 + lrow8;
      gload_lds16(gA + (size_t)R * H + k0 + csrc * 16, &ldsA[(wid * 4 + i) * 1024]);
      gload_lds16(gB + (size_t)R * H + k0 + csrc * 16, &ldsB[(wid * 4 + i) * 1024]);
    }
    __syncthreads();  // drains vmcnt -> LDS tiles ready
#pragma unroll
    for (int kk = 0; kk < 4; ++kk) {
      int cbyte = kk * 32 + (lane >> 4) * 8;
      int chunk = cbyte >> 4, rem = cbyte & 15;
      i64frag af[4], bfr[4];
#pragma unroll
      for (int m = 0; m < 4; ++m) {
        int row = wr * 64 + m * 16 + (lane & 15);
        af[m] = *(const i64frag*)&ldsA[row * BK + ((chunk ^ (row & 7)) << 4) + rem];
      }
#pragma unroll
      for (int n = 0; n < 4; ++n) {
        int row = wc * 64 + n * 16 + (lane & 15);
        bfr[n] = *(const i64frag*)&ldsB[row * BK + ((chunk ^ (row & 7)) << 4) + rem];
      }
#pragma unroll
      for (int m = 0; m < 4; ++m)
#pragma unroll
        for (int n = 0; n < 4; ++n)
          acc[m][n] = __builtin_amdgcn_mfma_f32_16x16x32_fp8_fp8(af[m], bfr[n], acc[m][n], 0, 0, 0);
    }
    __syncthreads();  // protect LDS before next stage
  }

  // epilogue: bias add, per-row strip max/sumexp, label extraction
  int cbase = nt * BN + wc * 64 + (lane & 15);
  float bv[4];
#pragma unroll
  for (int n = 0; n < 4; ++n) bv[n] = bias[cbase + n * 16];
  int strip = nt * 2 + wc;

#pragma unroll
  for (int m = 0; m < 4; ++m) {
#pragma unroll
    for (int j = 0; j < 4; ++j) {
      int tr = mt * BM + wr * 64 + m * 16 + (lane >> 4) * 4 + j;
      float v0 = acc[m][0][j] + bv[0];
      float v1 = acc[m][1][j] + bv[1];
      float v2 = acc[m][2][j] + bv[2];
      float v3 = acc[m][3][j] + bv[3];
      float rmax = fmaxf(fmaxf(v0, v1), fmaxf(v2, v3));
#pragma unroll
      for (int off = 8; off; off >>= 1) rmax = fmaxf(rmax, __shfl_xor(rmax, off));
      float s = expf(v0 - rmax) + expf(v1 - rmax) + expf(v2 - rmax) + expf(v3 - rmax);
#pragma unroll
      for (int off = 8; off; off >>= 1) s += __shfl_xor(s, off);
      if ((lane & 15) == 0) partials[(size_t)tr * NSTRIP + strip] = make_float2(rmax, s);
      int lbl = target[tr];
      if (lbl == cbase) label_logit[tr] = v0;
      else if (lbl == cbase + 16) label_logit[tr] = v1;
      else if (lbl == cbase + 32) label_logit[tr] = v2;
      else if (lbl == cbase + 48) label_logit[tr] = v3;
    }
  }
}

// ------------------------------------------------- per-token LSE combine
__global__ void lse_kernel(const float2* __restrict__ partials,
                           const float* __restrict__ label_logit,
                           const int* __restrict__ target,
                           float* __restrict__ token_logp) {
  int t = blockIdx.x;
  int lane = threadIdx.x;  // 64
  const float2* p = partials + (size_t)t * NSTRIP;
  float m = -INFINITY, s = 0.f;
  for (int i = lane; i < NSTRIP; i += 64) {
    float2 q = p[i];
    float nm = fmaxf(m, q.x);
    s = s * expf(m - nm) + q.y * expf(q.x - nm);
    m = nm;
  }
  float M2 = m;
#pragma unroll
  for (int off = 32; off; off >>= 1) M2 = fmaxf(M2, __shfl_xor(M2, off));
  float s2 = (m == -INFINITY) ? 0.f : s * expf(m - M2);
#pragma unroll
  for (int off = 32; off; off >>= 1) s2 += __shfl_xor(s2, off);
  if (lane == 0) {
    float lse = M2 + logf(s2);
    int lbl = target[t];
    token_logp[t] = (lbl != IGNORE_INDEX) ? (label_logit[t] - lse) : 0.f;
  }
}

// ------------------------------------------------- final scalar loss
__global__ void final_kernel(const float* __restrict__ token_logp,
                             const int* __restrict__ target,
                             float* __restrict__ out) {
  __shared__ float red[4];
  __shared__ float seq[8];
  int tid = threadIdx.x;  // 256
  int lane = tid & 63, w = tid >> 6;
  for (int b = 0; b < 8; ++b) {
    float s = 0.f;
    for (int t = tid; t < T; t += 256) s += token_logp[b * T + t];
#pragma unroll
    for (int off = 32; off; off >>= 1) s += __shfl_xor(s, off);
    if (lane == 0) red[w] = s;
    __syncthreads();
    if (tid == 0) seq[b] = red[0] + red[1] + red[2] + red[3];
    __syncthreads();
  }
  float c = 0.f;
  for (int t = tid; t < 4 * T; t += 256) c += (target[t] != IGNORE_INDEX) ? 1.f : 0.f;
#pragma unroll
  for (int off = 32; off; off >>= 1) c += __shfl_xor(c, off);
  if (lane == 0) red[w] = c;
  __syncthreads();
  if (tid == 0) {
    float cnt = red[0] + red[1] + red[2] + red[3];
    float nll = -(seq[0] + seq[1] + seq[2] + seq[3]) / cnt;
    float pref = 0.f;
    for (int i = 0; i < 4; ++i) {
      float d = BETA * (seq[i] - seq[i + 4]);
      float ls = fminf(d, 0.f) - log1pf(expf(-fabsf(d)));  // log_sigmoid(d)
      pref += -ls;
    }
    pref *= 0.25f;
    out[0] = nll + pref;
  }
}

extern "C" void kernel_launch(void* const* d_in, const int* in_sizes, int n_in,
                              void* d_out, int out_size, void* d_ws, size_t ws_size,
                              hipStream_t stream) {
  const float* lin_weight = (const float*)d_in[0];  // [V][H]
  const float* input = (const float*)d_in[1];       // [B][T][H]
  const int* target = (const int*)d_in[2];          // [B][T]
  const float* bias = (const float*)d_in[3];        // [V]
  float* out = (float*)d_out;

  char* ws = (char*)d_ws;
  unsigned char* Af8 = (unsigned char*)ws;
  size_t o = (size_t)M * H;
  unsigned char* Wf8 = (unsigned char*)(ws + o);
  o += (size_t)V * H;
  float2* partials = (float2*)(ws + o);
  o += (size_t)M * NSTRIP * 8;
  float* label_logit = (float*)(ws + o);
  o += (size_t)M * 4;
  float* token_logp = (float*)(ws + o);

  cvt_fp8_kernel<<<2048, 256, 0, stream>>>(input, (uint2*)Af8, M * H / 8);
  cvt_fp8_kernel<<<4096, 256, 0, stream>>>(lin_weight, (uint2*)Wf8, V * H / 8);
  gemm_lse_kernel<<<MT * NT, 256, 0, stream>>>(Af8, Wf8, bias, target, partials, label_logit);
  lse_kernel<<<M, 64, 0, stream>>>(partials, label_logit, target, token_logp);
  final_kernel<<<1, 256, 0, stream>>>(token_logp, target, out);
}

// Round 3
// 1495.395 us; speedup vs baseline: 2.5768x; 1.5736x over previous
//
#include <hip/hip_runtime.h>
#include <hip/hip_bf16.h>
#include <math.h>

#define IGNORE_INDEX (-100)
#define BETA 0.1f

typedef float f32x4 __attribute__((ext_vector_type(4)));
typedef int i32x8 __attribute__((ext_vector_type(8)));

static constexpr int Bsz = 8, T = 1024, H = 4096, V = 32000;
static constexpr int M = Bsz * T;       // 8192 tokens
static constexpr int BM = 128, BN = 128, BK = 128;  // BK in fp8 bytes (K=128)
static constexpr int MT = M / BM;       // 64
static constexpr int NT = V / BN;       // 250
static constexpr int NSTRIP = NT * 2;   // 500 strips of 64 cols

// ------------------------------------------------- fp32 -> fp8 e4m3 (packed)
__global__ void cvt_fp8_kernel(const float* __restrict__ src,
                               uint2* __restrict__ dst, int n8) {
  int stride = gridDim.x * blockDim.x;
  for (int g = blockIdx.x * blockDim.x + threadIdx.x; g < n8; g += stride) {
    const float4* s = (const float4*)(src + (size_t)g * 8);
    float4 v0 = s[0], v1 = s[1];
    int r0 = __builtin_amdgcn_cvt_pk_fp8_f32(v0.x, v0.y, 0, false);
    r0 = __builtin_amdgcn_cvt_pk_fp8_f32(v0.z, v0.w, r0, true);
    int r1 = __builtin_amdgcn_cvt_pk_fp8_f32(v1.x, v1.y, 0, false);
    r1 = __builtin_amdgcn_cvt_pk_fp8_f32(v1.z, v1.w, r1, true);
    dst[g] = make_uint2((unsigned)r0, (unsigned)r1);
  }
}

__device__ inline void gload_lds16(const void* g, void* l) {
  __builtin_amdgcn_global_load_lds(
      (const __attribute__((address_space(1))) void*)g,
      (__attribute__((address_space(3))) void*)l, 16, 0, 0);
}

// --------------------------------------- fused MX-fp8 GEMM + strip-LSE
// A: [M][H] fp8, W: [V][H] fp8 (B^T layout), bias fp32[V]
// MFMA: mfma_scale_f32_16x16x128_f8f6f4 with unit scales (E8M0 0x7F = x1.0,
// bit-identical to plain fp8 matmul, 2x the MFMA rate).
// T2 swizzle: global source chunk pre-permuted (chunk ^= row&7), LDS linear,
// ds_read applies the same XOR -> both-sides involution (rule 21).
__global__ __launch_bounds__(256) void gemm_lse_kernel(
    const unsigned char* __restrict__ A, const unsigned char* __restrict__ W,
    const float* __restrict__ bias, const int* __restrict__ target,
    float2* __restrict__ partials, float* __restrict__ label_logit) {
  __shared__ unsigned char ldsA[BM * BK];
  __shared__ unsigned char ldsB[BN * BK];

  // bijective XCD swizzle (16000 % 8 == 0), mt-fastest for W-panel L2 reuse
  int bid = blockIdx.x;
  int swz = (bid & 7) * (MT * NT / 8) + (bid >> 3);
  int mt = swz % MT;
  int nt = swz / MT;

  int tid = threadIdx.x;
  int lane = tid & 63;
  int wid = tid >> 6;               // 4 waves
  int wr = wid >> 1, wc = wid & 1;  // 2x2 wave grid, 64x64 each

  f32x4 acc[4][4];
#pragma unroll
  for (int m = 0; m < 4; ++m)
#pragma unroll
    for (int n = 0; n < 4; ++n) acc[m][n] = (f32x4){0.f, 0.f, 0.f, 0.f};

  int lrow8 = lane >> 3;             // row within the 8-row staging stripe
  int csrc = (lane & 7) ^ lrow8;     // pre-swizzled source chunk (R&7 == lrow8)
  const unsigned char* gA = A + (size_t)(mt * BM) * H;
  const unsigned char* gB = W + (size_t)(nt * BN) * H;

  for (int kt = 0; kt < H / BK; ++kt) {
    size_t k0 = (size_t)kt * BK;
#pragma unroll
    for (int i = 0; i < 4; ++i) {
      int R = (wid * 4 + i) * 8 + lrow8;
      gload_lds16(gA + (size_t)R * H + k0 + csrc * 16, &ldsA[(wid * 4 + i) * 1024]);
      gload_lds16(gB + (size_t)R * H + k0 + csrc * 16, &ldsB[(wid * 4 + i) * 1024]);
    }
    __syncthreads();  // drains vmcnt -> LDS tiles ready

    // each lane: 32 consecutive k-bytes at (lane>>4)*32, via 2x b128 through
    // the same XOR involution
    i32x8 af[4], bfr[4];
    int cb = (lane >> 4) * 2;  // even base chunk
#pragma unroll
    for (int m = 0; m < 4; ++m) {
      int row = wr * 64 + m * 16 + (lane & 15);
      const unsigned char* base = &ldsA[row * BK];
      int4 lo = *(const int4*)(base + (((cb) ^ (row & 7)) << 4));
      int4 hi = *(const int4*)(base + (((cb + 1) ^ (row & 7)) << 4));
      af[m] = (i32x8){lo.x, lo.y, lo.z, lo.w, hi.x, hi.y, hi.z, hi.w};
    }
#pragma unroll
    for (int n = 0; n < 4; ++n) {
      int row = wc * 64 + n * 16 + (lane & 15);
      const unsigned char* base = &ldsB[row * BK];
      int4 lo = *(const int4*)(base + (((cb) ^ (row & 7)) << 4));
      int4 hi = *(const int4*)(base + (((cb + 1) ^ (row & 7)) << 4));
      bfr[n] = (i32x8){lo.x, lo.y, lo.z, lo.w, hi.x, hi.y, hi.z, hi.w};
    }
#pragma unroll
    for (int m = 0; m < 4; ++m)
#pragma unroll
      for (int n = 0; n < 4; ++n)
        acc[m][n] = __builtin_amdgcn_mfma_scale_f32_16x16x128_f8f6f4(
            af[m], bfr[n], acc[m][n], 0, 0, 0, 0x7F7F7F7Fu, 0, 0x7F7F7F7Fu);
    __syncthreads();  // protect LDS before next stage
  }

  // epilogue: bias add, per-row strip max/sumexp, label extraction
  int cbase = nt * BN + wc * 64 + (lane & 15);
  float bv[4];
#pragma unroll
  for (int n = 0; n < 4; ++n) bv[n] = bias[cbase + n * 16];
  int strip = nt * 2 + wc;

#pragma unroll
  for (int m = 0; m < 4; ++m) {
#pragma unroll
    for (int j = 0; j < 4; ++j) {
      int tr = mt * BM + wr * 64 + m * 16 + (lane >> 4) * 4 + j;
      float v0 = acc[m][0][j] + bv[0];
      float v1 = acc[m][1][j] + bv[1];
      float v2 = acc[m][2][j] + bv[2];
      float v3 = acc[m][3][j] + bv[3];
      float rmax = fmaxf(fmaxf(v0, v1), fmaxf(v2, v3));
#pragma unroll
      for (int off = 8; off; off >>= 1) rmax = fmaxf(rmax, __shfl_xor(rmax, off));
      float s = expf(v0 - rmax) + expf(v1 - rmax) + expf(v2 - rmax) + expf(v3 - rmax);
#pragma unroll
      for (int off = 8; off; off >>= 1) s += __shfl_xor(s, off);
      if ((lane & 15) == 0) partials[(size_t)tr * NSTRIP + strip] = make_float2(rmax, s);
      int lbl = target[tr];
      if (lbl == cbase) label_logit[tr] = v0;
      else if (lbl == cbase + 16) label_logit[tr] = v1;
      else if (lbl == cbase + 32) label_logit[tr] = v2;
      else if (lbl == cbase + 48) label_logit[tr] = v3;
    }
  }
}

// ------------------------------------------------- per-token LSE combine
__global__ void lse_kernel(const float2* __restrict__ partials,
                           const float* __restrict__ label_logit,
                           const int* __restrict__ target,
                           float* __restrict__ token_logp) {
  int t = blockIdx.x;
  int lane = threadIdx.x;  // 64
  const float2* p = partials + (size_t)t * NSTRIP;
  float m = -INFINITY, s = 0.f;
  for (int i = lane; i < NSTRIP; i += 64) {
    float2 q = p[i];
    float nm = fmaxf(m, q.x);
    s = s * expf(m - nm) + q.y * expf(q.x - nm);
    m = nm;
  }
  float M2 = m;
#pragma unroll
  for (int off = 32; off; off >>= 1) M2 = fmaxf(M2, __shfl_xor(M2, off));
  float s2 = (m == -INFINITY) ? 0.f : s * expf(m - M2);
#pragma unroll
  for (int off = 32; off; off >>= 1) s2 += __shfl_xor(s2, off);
  if (lane == 0) {
    float lse = M2 + logf(s2);
    int lbl = target[t];
    token_logp[t] = (lbl != IGNORE_INDEX) ? (label_logit[t] - lse) : 0.f;
  }
}

// ------------------------------------------------- final scalar loss
__global__ void final_kernel(const float* __restrict__ token_logp,
                             const int* __restrict__ target,
                             float* __restrict__ out) {
  __shared__ float red[4];
  __shared__ float seq[8];
  int tid = threadIdx.x;  // 256
  int lane = tid & 63, w = tid >> 6;
  for (int b = 0; b < 8; ++b) {
    float s = 0.f;
    for (int t = tid; t < T; t += 256) s += token_logp[b * T + t];
#pragma unroll
    for (int off = 32; off; off >>= 1) s += __shfl_xor(s, off);
    if (lane == 0) red[w] = s;
    __syncthreads();
    if (tid == 0) seq[b] = red[0] + red[1] + red[2] + red[3];
    __syncthreads();
  }
  float c = 0.f;
  for (int t = tid; t < 4 * T; t += 256) c += (target[t] != IGNORE_INDEX) ? 1.f : 0.f;
#pragma unroll
  for (int off = 32; off; off >>= 1) c += __shfl_xor(c, off);
  if (lane == 0) red[w] = c;
  __syncthreads();
  if (tid == 0) {
    float cnt = red[0] + red[1] + red[2] + red[3];
    float nll = -(seq[0] + seq[1] + seq[2] + seq[3]) / cnt;
    float pref = 0.f;
    for (int i = 0; i < 4; ++i) {
      float d = BETA * (seq[i] - seq[i + 4]);
      float ls = fminf(d, 0.f) - log1pf(expf(-fabsf(d)));  // log_sigmoid(d)
      pref += -ls;
    }
    pref *= 0.25f;
    out[0] = nll + pref;
  }
}

extern "C" void kernel_launch(void* const* d_in, const int* in_sizes, int n_in,
                              void* d_out, int out_size, void* d_ws, size_t ws_size,
                              hipStream_t stream) {
  const float* lin_weight = (const float*)d_in[0];  // [V][H]
  const float* input = (const float*)d_in[1];       // [B][T][H]
  const int* target = (const int*)d_in[2];          // [B][T]
  const float* bias = (const float*)d_in[3];        // [V]
  float* out = (float*)d_out;

  char* ws = (char*)d_ws;
  unsigned char* Af8 = (unsigned char*)ws;
  size_t o = (size_t)M * H;
  unsigned char* Wf8 = (unsigned char*)(ws + o);
  o += (size_t)V * H;
  float2* partials = (float2*)(ws + o);
  o += (size_t)M * NSTRIP * 8;
  float* label_logit = (float*)(ws + o);
  o += (size_t)M * 4;
  float* token_logp = (float*)(ws + o);

  cvt_fp8_kernel<<<2048, 256, 0, stream>>>(input, (uint2*)Af8, M * H / 8);
  cvt_fp8_kernel<<<4096, 256, 0, stream>>>(lin_weight, (uint2*)Wf8, V * H / 8);
  gemm_lse_kernel<<<MT * NT, 256, 0, stream>>>(Af8, Wf8, bias, target, partials, label_logit);
  lse_kernel<<<M, 64, 0, stream>>>(partials, label_logit, target, token_logp);
  final_kernel<<<1, 256, 0, stream>>>(token_logp, target, out);
}